// Round 8
// baseline (486.577 us; speedup 1.0000x reference)
//
#include <hip/hip_runtime.h>
#include <math.h>

#define D_DIM 128
#define H_DIM 256
#define W_DIM 256
#define HW (H_DIM * W_DIM)
#define HW4 (HW / 4)
#define NIMG 2
#define NPI (D_DIM * HW)
#define NTOT (NIMG * NPI)

#define TDZ 16
#define TH 16
#define TW 32

#define AW4 10   // aS chunks/row: chunk c -> gx = x0-4+4c  (x0-4 .. x0+35)
#define AH 20    // aS rows: gy = y0-2 .. y0+17
#define EW4 9    // eT chunks/row: chunk c -> gx = x0-2+4c  (x0-2 .. x0+33)
#define EH 18    // eT rows: gy = y0-1 .. y0+16

#define NLOAD (AH * AW4)      // 200
#define NERO  (EH * EW4)      // 162
#define NOUT  (TH * (TW/4))   // 128

#define NUM_ITER 20
#define STOP_THRESH 1e-4

__device__ __forceinline__ float min3f(float a, float b, float c) { return fminf(fminf(a, b), c); }
__device__ __forceinline__ float max3f(float a, float b, float c) { return fmaxf(fmaxf(a, b), c); }
__device__ __forceinline__ float leaky(float x) { return fmaxf(x, 0.01f * x); }

__global__ void init_slots(double* slots) {
    if (threadIdx.x < 32) slots[threadIdx.x] = 0.0;
}

// f4-granular rolling-slice fused step (R7 structure), tile 32x16x16 so the
// grid reaches 2048 blocks (8/CU). Roles on contiguous thread ranges
// (conflict-free b128); load role rotated to threads [56,256) to interleave
// wave roles:
//   load  (t-56 in [0,200)) : stage slice window into aS4 (ping-pong), prefetch
//   erode (t in [0,162))    : 6x b128 -> vert min3 -> slide min3 -> rolling
//                             D-min regs -> masked eroded slice to eT4
//   out   (t in [0,128))    : 6x b128 -> vert max3 -> slide max3 -> rolling
//                             D-max regs -> delta/skel update; a_out = erosion
__global__ __launch_bounds__(256) void skel_step(
    const float* __restrict__ a_in,
    float* __restrict__ a_out,
    float* __restrict__ skel,
    double* __restrict__ slots,
    int step)
{
    __shared__ float4 aS4[2][NLOAD];   // 6400 B
    __shared__ float4 eT4[NERO];       // 2592 B
    __shared__ float wsum[4];
    __shared__ int s_active;

    const int t = threadIdx.x;

    if (t == 0) {
        int act = 1;
        for (int j = 1; j < step; ++j)
            if (!(slots[j] >= STOP_THRESH * (double)NTOT)) { act = 0; break; }
        s_active = act;
    }
    __syncthreads();
    if (!s_active) return;

    const int bx = blockIdx.x, by = blockIdx.y;
    const int bz = blockIdx.z & 7, img = blockIdx.z >> 3;
    const int x0 = bx * TW, y0 = by * TH, z0 = bz * TDZ;

    const float* in = a_in + (size_t)img * NPI;
    float4* aout4 = (float4*)(a_out + (size_t)img * NPI);
    float4* sk4 = (float4*)(skel + (size_t)img * NPI);

    // ---- load item (rotated: threads 56..255) ----
    const int li = t - 56;
    const bool isL = (li >= 0);        // li in [0, 200)
    int lOff = 0, lWr = 0; bool lVal = false;
    {
        int q = isL ? li : 0;
        int lr = q / AW4, lc = q - lr * AW4;
        int gy = y0 - 2 + lr, gx = x0 - 4 + 4 * lc;
        lVal = isL && ((unsigned)gy < H_DIM) && ((unsigned)gx <= (unsigned)(W_DIM - 4));
        lOff = gy * W_DIM + gx;
        lWr = q;
    }

    // ---- erode item (t < 162) ----
    const bool isE = t < NERO;
    int eRd = 0; bool sA = false, sB = false, sC = false, sD = false;
    {
        int q = isE ? t : 0;
        int mh = q / EW4, ej = q - mh * EW4;
        eRd = mh * AW4 + ej;
        int gy = y0 - 1 + mh;
        bool gok = (unsigned)gy < H_DIM;
        int gxb = x0 - 2 + 4 * ej;
        sA = gok && ((unsigned)(gxb + 0) < W_DIM);
        sB = gok && ((unsigned)(gxb + 1) < W_DIM);
        sC = gok && ((unsigned)(gxb + 2) < W_DIM);
        sD = gok && ((unsigned)(gxb + 3) < W_DIM);
    }

    // ---- out item (t < 128) ----
    const bool isO = t < NOUT;
    int oRd = 0, oAc = 0;
    size_t ob = 0;
    {
        int q = isO ? t : 0;
        int oh = q >> 3, wq = q & 7;
        oRd = oh * EW4 + wq;
        oAc = (oh + 2) * AW4 + wq + 1;
        ob = ((size_t)z0 * HW + (size_t)(y0 + oh) * W_DIM + (size_t)x0) / 4 + wq;
    }

    const float INF = INFINITY;
    const float4 inf4 = make_float4(INF, INF, INF, INF);
    const float4 ninf4 = make_float4(-INF, -INF, -INF, -INF);
    float4 mP2 = inf4, mP1 = inf4;
    float4 xP2 = ninf4, xP1 = ninf4;
    float4 acA = make_float4(0, 0, 0, 0), acB = acA, ecA = acA;
    float lsum = 0.f;

    // initial prefetch: slice zl = z0-2
    float4 pf = inf4;
    {
        int z = z0 - 2;
        if ((unsigned)z < D_DIM && lVal)
            pf = *(const float4*)(in + (size_t)z * HW + lOff);
    }

    for (int i = 0; i < TDZ + 4; ++i) {
        const int cur = i & 1;

        if (isL) aS4[cur][lWr] = pf;
        __syncthreads();   // B1: aS4[cur] ready

        // next prefetch (hides HBM latency under erode+out)
        pf = inf4;
        {
            int z = z0 - 1 + i;
            if (i < TDZ + 3 && (unsigned)z < D_DIM && lVal)
                pf = *(const float4*)(in + (size_t)z * HW + lOff);
        }

        const bool zp = (unsigned)(z0 - 3 + i) < D_DIM;   // erosion slice in volume?

        float4 aCn;
        if (isO) aCn = aS4[cur][oAc];

        // ---- erode ----
        if (isE) {
            const float4* s = aS4[cur];
            float4 a0 = s[eRd],           b0 = s[eRd + 1];
            float4 a1 = s[eRd + AW4],     b1 = s[eRd + AW4 + 1];
            float4 a2 = s[eRd + 2 * AW4], b2 = s[eRd + 2 * AW4 + 1];
            float4 va, vb, mC;
            va.x = min3f(a0.x, a1.x, a2.x);
            va.y = min3f(a0.y, a1.y, a2.y);
            va.z = min3f(a0.z, a1.z, a2.z);
            va.w = min3f(a0.w, a1.w, a2.w);
            vb.x = min3f(b0.x, b1.x, b2.x);
            vb.y = min3f(b0.y, b1.y, b2.y);
            vb.z = min3f(b0.z, b1.z, b2.z);
            mC.x = min3f(va.y, va.z, va.w);
            mC.y = min3f(va.z, va.w, vb.x);
            mC.z = min3f(va.w, vb.x, vb.y);
            mC.w = min3f(vb.x, vb.y, vb.z);
            if (i >= 2 && zp) {
                float4 e;
                e.x = sA ? min3f(mP2.x, mP1.x, mC.x) : -INF;
                e.y = sB ? min3f(mP2.y, mP1.y, mC.y) : -INF;
                e.z = sC ? min3f(mP2.z, mP1.z, mC.z) : -INF;
                e.w = sD ? min3f(mP2.w, mP1.w, mC.w) : -INF;
                eT4[t] = e;
            }
            mP2 = mP1; mP1 = mC;
        }
        __syncthreads();   // B2: eT4 ready

        // ---- out ----
        if (isO) {
            float4 xC, ecB;
            if (i >= 2 && zp) {
                float4 A0 = eT4[oRd],           B0 = eT4[oRd + 1];
                float4 A1 = eT4[oRd + EW4],     B1 = eT4[oRd + EW4 + 1];
                float4 A2 = eT4[oRd + 2 * EW4], B2 = eT4[oRd + 2 * EW4 + 1];
                float4 va, vb;
                va.x = max3f(A0.x, A1.x, A2.x);
                va.y = max3f(A0.y, A1.y, A2.y);
                va.z = max3f(A0.z, A1.z, A2.z);
                va.w = max3f(A0.w, A1.w, A2.w);
                vb.x = max3f(B0.x, B1.x, B2.x);
                vb.y = max3f(B0.y, B1.y, B2.y);
                vb.z = max3f(B0.z, B1.z, B2.z);
                xC.x = max3f(va.y, va.z, va.w);
                xC.y = max3f(va.z, va.w, vb.x);
                xC.z = max3f(va.w, vb.x, vb.y);
                xC.w = max3f(vb.x, vb.y, vb.z);
                ecB.x = A1.z; ecB.y = A1.w; ecB.z = B1.x; ecB.w = B1.y;
            } else {
                xC = ninf4; ecB = ninf4;
            }

            if (i >= 4) {
                float4 dl;
                dl.x = leaky(acA.x - max3f(xP2.x, xP1.x, xC.x));
                dl.y = leaky(acA.y - max3f(xP2.y, xP1.y, xC.y));
                dl.z = leaky(acA.z - max3f(xP2.z, xP1.z, xC.z));
                dl.w = leaky(acA.w - max3f(xP2.w, xP1.w, xC.w));
                if (step < NUM_ITER) aout4[ob] = ecA;
                if (step == 0) {
                    sk4[ob] = dl;
                } else {
                    float4 gg = sk4[ob];
                    float4 up, gn;
                    up.x = leaky(dl.x - gg.x * dl.x); gn.x = gg.x + up.x;
                    up.y = leaky(dl.y - gg.y * dl.y); gn.y = gg.y + up.y;
                    up.z = leaky(dl.z - gg.z * dl.z); gn.z = gg.z + up.z;
                    up.w = leaky(dl.w - gg.w * dl.w); gn.w = gg.w + up.w;
                    sk4[ob] = gn;
                    if (step == 1)
                        lsum += fabsf(gn.x) + fabsf(gn.y) + fabsf(gn.z) + fabsf(gn.w);
                    else
                        lsum += fabsf(up.x) + fabsf(up.y) + fabsf(up.z) + fabsf(up.w);
                }
                ob += HW4;
            }
            xP2 = xP1; xP1 = xC;
            acA = acB; acB = aCn;
            ecA = ecB;
        }
    }

    // dn reduction: one double atomic per block
    if (step > 0) {
        #pragma unroll
        for (int off = 32; off > 0; off >>= 1)
            lsum += __shfl_down(lsum, off, 64);
        const int lane = t & 63, wid = t >> 6;
        if (lane == 0) wsum[wid] = lsum;
        __syncthreads();
        if (t == 0) {
            float b = wsum[0] + wsum[1] + wsum[2] + wsum[3];
            atomicAdd(&slots[step], (double)b);
        }
    }
}

extern "C" void kernel_launch(void* const* d_in, const int* in_sizes, int n_in,
                              void* d_out, int out_size, void* d_ws, size_t ws_size,
                              hipStream_t stream) {
    const float* img = (const float*)d_in[0];
    float* out = (float*)d_out;
    float* buf0 = (float*)d_ws;
    float* buf1 = buf0 + NTOT;
    double* slots = (double*)(buf1 + NTOT);

    init_slots<<<1, 64, 0, stream>>>(slots);

    dim3 grid(W_DIM / TW, H_DIM / TH, (D_DIM / TDZ) * NIMG);
    for (int s = 0; s <= NUM_ITER; ++s) {
        const float* ain = (s == 0) ? img : ((s & 1) ? buf0 : buf1);
        float* aout = (s & 1) ? buf1 : buf0;
        skel_step<<<grid, 256, 0, stream>>>(ain, aout, out, slots, s);
    }
}

// Round 9
// 443.142 us; speedup vs baseline: 1.0980x; 1.0980x over previous
//
#include <hip/hip_runtime.h>
#include <math.h>

#define D_DIM 128
#define H_DIM 256
#define W_DIM 256
#define HW (H_DIM * W_DIM)
#define HW4 (HW / 4)
#define NIMG 2
#define NPI (D_DIM * HW)
#define NTOT (NIMG * NPI)

#define TDZ 16
#define TH 16
#define TW 64

#define AW4 18   // aS chunks/row: chunk c -> gx = x0-4+4c  (x0-4 .. x0+67)
#define AH 20    // aS rows: gy = y0-2 .. y0+17
#define EW4 17   // eT chunks/row: chunk c -> gx = x0-2+4c  (x0-2 .. x0+65)
#define EH 18    // eT rows: gy = y0-1 .. y0+16

#define NLOAD (AH * AW4)      // 360
#define NERO  (EH * EW4)      // 306
#define NOUT  (TH * (TW/4))   // 256

#define NUM_ITER 20
#define STOP_THRESH 1e-4

__device__ __forceinline__ float min3f(float a, float b, float c) { return fminf(fminf(a, b), c); }
__device__ __forceinline__ float max3f(float a, float b, float c) { return fmaxf(fmaxf(a, b), c); }
__device__ __forceinline__ float leaky(float x) { return fmaxf(x, 0.01f * x); }

__global__ void init_slots(double* slots) {
    if (threadIdx.x < 32) slots[threadIdx.x] = 0.0;
}

// Single-barrier-per-slice pipeline (out lags erode by one slice via eT4
// ping-pong), 2-slice-deep global prefetch. Tile 64x16x16, all 256 threads
// active in every stage:
//   iter i: commit aS4[cur] (a-slice z0-2+i) -> BARRIER ->
//           erode(aS4[cur]) -> eT4[cur] (erosion z0-3+i)
//           out(eT4[cur^1])  (erosion z0-4+i; output z0-5+i when i>=5)
__global__ __launch_bounds__(256) void skel_step(
    const float* __restrict__ a_in,
    float* __restrict__ a_out,
    float* __restrict__ skel,
    double* __restrict__ slots,
    int step)
{
    __shared__ float4 aS4[2][NLOAD];   // 11520 B
    __shared__ float4 eT4[2][NERO];    // 9792 B
    __shared__ float wsum[4];
    __shared__ int s_active;

    const int t = threadIdx.x;

    if (t == 0) {
        int act = 1;
        for (int j = 1; j < step; ++j)
            if (!(slots[j] >= STOP_THRESH * (double)NTOT)) { act = 0; break; }
        s_active = act;
    }
    __syncthreads();
    if (!s_active) return;

    const int bx = blockIdx.x, by = blockIdx.y;
    const int bz = blockIdx.z & 7, img = blockIdx.z >> 3;
    const int x0 = bx * TW, y0 = by * TH, z0 = bz * TDZ;

    const float* in = a_in + (size_t)img * NPI;
    float4* aout4 = (float4*)(a_out + (size_t)img * NPI);
    float4* sk4 = (float4*)(skel + (size_t)img * NPI);

    // ---- load items ----
    int lOff0, lOff1 = 0; bool lVal0, lVal1 = false;
    {
        int lr = t / AW4, lc = t - lr * AW4;
        int gy = y0 - 2 + lr, gx = x0 - 4 + 4 * lc;
        lVal0 = ((unsigned)gy < H_DIM) && ((unsigned)gx <= (unsigned)(W_DIM - 4));
        lOff0 = gy * W_DIM + gx;
    }
    const bool hasL1 = t < (NLOAD - 256);   // t < 104
    if (hasL1) {
        int q = t + 256;
        int lr = q / AW4, lc = q - lr * AW4;
        int gy = y0 - 2 + lr, gx = x0 - 4 + 4 * lc;
        lVal1 = ((unsigned)gy < H_DIM) && ((unsigned)gx <= (unsigned)(W_DIM - 4));
        lOff1 = gy * W_DIM + gx;
    }

    // ---- erode items ----
    int eRd0; bool sA0, sB0, sC0, sD0;
    {
        int mh = t / EW4, ej = t - mh * EW4;
        eRd0 = mh * AW4 + ej;
        int gy = y0 - 1 + mh;
        bool gok = (unsigned)gy < H_DIM;
        int gxb = x0 - 2 + 4 * ej;
        sA0 = gok && ((unsigned)(gxb + 0) < W_DIM);
        sB0 = gok && ((unsigned)(gxb + 1) < W_DIM);
        sC0 = gok && ((unsigned)(gxb + 2) < W_DIM);
        sD0 = gok && ((unsigned)(gxb + 3) < W_DIM);
    }
    const bool hasE1 = t < (NERO - 256);    // t < 50
    int eRd1 = 0; bool sA1 = false, sB1 = false, sC1 = false, sD1 = false;
    if (hasE1) {
        int q = t + 256;
        int mh = q / EW4, ej = q - mh * EW4;
        eRd1 = mh * AW4 + ej;
        int gy = y0 - 1 + mh;
        bool gok = (unsigned)gy < H_DIM;
        int gxb = x0 - 2 + 4 * ej;
        sA1 = gok && ((unsigned)(gxb + 0) < W_DIM);
        sB1 = gok && ((unsigned)(gxb + 1) < W_DIM);
        sC1 = gok && ((unsigned)(gxb + 2) < W_DIM);
        sD1 = gok && ((unsigned)(gxb + 3) < W_DIM);
    }

    // ---- out item ----
    const int oh = t >> 4, wq = t & 15;
    const int oRd = oh * EW4 + wq;
    const int oAc = (oh + 2) * AW4 + wq + 1;
    size_t ob = ((size_t)z0 * HW + (size_t)(y0 + oh) * W_DIM + (size_t)x0) / 4 + wq;

    const float INF = INFINITY;
    const float4 inf4 = make_float4(INF, INF, INF, INF);
    const float4 ninf4 = make_float4(-INF, -INF, -INF, -INF);
    float4 m0P2 = inf4, m0P1 = inf4, m1P2 = inf4, m1P1 = inf4;
    float4 xP2 = ninf4, xP1 = ninf4;
    float4 acA = make_float4(0, 0, 0, 0), acB = acA, acC = acA, ecA = acA;
    float lsum = 0.f;

    // 2-deep prefetch: pfA = slice 0 (z0-2), pfB = slice 1 (z0-1)
    float4 pfA0 = inf4, pfA1 = inf4, pfB0 = inf4, pfB1 = inf4;
    {
        int z = z0 - 2;
        if ((unsigned)z < D_DIM) {
            const float* p = in + (size_t)z * HW;
            if (lVal0) pfA0 = *(const float4*)(p + lOff0);
            if (lVal1) pfA1 = *(const float4*)(p + lOff1);
        }
        z = z0 - 1;
        if ((unsigned)z < D_DIM) {
            const float* p = in + (size_t)z * HW;
            if (lVal0) pfB0 = *(const float4*)(p + lOff0);
            if (lVal1) pfB1 = *(const float4*)(p + lOff1);
        }
    }

    for (int i = 0; i < TDZ + 5; ++i) {
        const int cur = i & 1;

        // phase A: commit slice i (a-slice z0-2+i)
        if (i <= TDZ + 3) {
            aS4[cur][t] = pfA0;
            if (hasL1) aS4[cur][t + 256] = pfA1;
        }
        __syncthreads();   // the ONE barrier per slice

        // rotate prefetch pipe; issue load for slice i+2 (2-iteration cover)
        pfA0 = pfB0; pfA1 = pfB1;
        pfB0 = inf4; pfB1 = inf4;
        if (i <= TDZ + 1) {
            int z = z0 + i;            // slice i+2 -> z = z0-2+(i+2)
            if ((unsigned)z < D_DIM) {
                const float* p = in + (size_t)z * HW;
                if (lVal0) pfB0 = *(const float4*)(p + lOff0);
                if (lVal1) pfB1 = *(const float4*)(p + lOff1);
            }
        }

        const bool zpE = (unsigned)(z0 - 3 + i) < D_DIM;   // erosion slice (erode phase)
        const bool zpO = (unsigned)(z0 - 4 + i) < D_DIM;   // erosion slice (out phase)

        // ---- erode: a-slices (i-2,i-1,i) -> erosion z0-3+i -> eT4[cur] ----
        {
            const float4* s = aS4[cur];
            float4 a0 = s[eRd0],           b0 = s[eRd0 + 1];
            float4 a1 = s[eRd0 + AW4],     b1 = s[eRd0 + AW4 + 1];
            float4 a2 = s[eRd0 + 2 * AW4], b2 = s[eRd0 + 2 * AW4 + 1];
            float4 va, vb, mC;
            va.x = min3f(a0.x, a1.x, a2.x);
            va.y = min3f(a0.y, a1.y, a2.y);
            va.z = min3f(a0.z, a1.z, a2.z);
            va.w = min3f(a0.w, a1.w, a2.w);
            vb.x = min3f(b0.x, b1.x, b2.x);
            vb.y = min3f(b0.y, b1.y, b2.y);
            vb.z = min3f(b0.z, b1.z, b2.z);
            mC.x = min3f(va.y, va.z, va.w);
            mC.y = min3f(va.z, va.w, vb.x);
            mC.z = min3f(va.w, vb.x, vb.y);
            mC.w = min3f(vb.x, vb.y, vb.z);
            if (i >= 2 && zpE) {
                float4 e;
                e.x = sA0 ? min3f(m0P2.x, m0P1.x, mC.x) : -INF;
                e.y = sB0 ? min3f(m0P2.y, m0P1.y, mC.y) : -INF;
                e.z = sC0 ? min3f(m0P2.z, m0P1.z, mC.z) : -INF;
                e.w = sD0 ? min3f(m0P2.w, m0P1.w, mC.w) : -INF;
                eT4[cur][t] = e;
            }
            m0P2 = m0P1; m0P1 = mC;
        }
        if (hasE1) {
            const float4* s = aS4[cur];
            float4 a0 = s[eRd1],           b0 = s[eRd1 + 1];
            float4 a1 = s[eRd1 + AW4],     b1 = s[eRd1 + AW4 + 1];
            float4 a2 = s[eRd1 + 2 * AW4], b2 = s[eRd1 + 2 * AW4 + 1];
            float4 va, vb, mC;
            va.x = min3f(a0.x, a1.x, a2.x);
            va.y = min3f(a0.y, a1.y, a2.y);
            va.z = min3f(a0.z, a1.z, a2.z);
            va.w = min3f(a0.w, a1.w, a2.w);
            vb.x = min3f(b0.x, b1.x, b2.x);
            vb.y = min3f(b0.y, b1.y, b2.y);
            vb.z = min3f(b0.z, b1.z, b2.z);
            mC.x = min3f(va.y, va.z, va.w);
            mC.y = min3f(va.z, va.w, vb.x);
            mC.z = min3f(va.w, vb.x, vb.y);
            mC.w = min3f(vb.x, vb.y, vb.z);
            if (i >= 2 && zpE) {
                float4 e;
                e.x = sA1 ? min3f(m1P2.x, m1P1.x, mC.x) : -INF;
                e.y = sB1 ? min3f(m1P2.y, m1P1.y, mC.y) : -INF;
                e.z = sC1 ? min3f(m1P2.z, m1P1.z, mC.z) : -INF;
                e.w = sD1 ? min3f(m1P2.w, m1P1.w, mC.w) : -INF;
                eT4[cur][t + 256] = e;
            }
            m1P2 = m1P1; m1P1 = mC;
        }

        // ---- out: dilate erosion slice z0-4+i from eT4[cur^1]; output z0-5+i ----
        {
            const float4 aCn = aS4[cur][oAc];
            float4 xC, ecB;
            if (i >= 3 && zpO) {
                const float4* eP = eT4[cur ^ 1];
                float4 A0 = eP[oRd],           B0 = eP[oRd + 1];
                float4 A1 = eP[oRd + EW4],     B1 = eP[oRd + EW4 + 1];
                float4 A2 = eP[oRd + 2 * EW4], B2 = eP[oRd + 2 * EW4 + 1];
                float4 va, vb;
                va.x = max3f(A0.x, A1.x, A2.x);
                va.y = max3f(A0.y, A1.y, A2.y);
                va.z = max3f(A0.z, A1.z, A2.z);
                va.w = max3f(A0.w, A1.w, A2.w);
                vb.x = max3f(B0.x, B1.x, B2.x);
                vb.y = max3f(B0.y, B1.y, B2.y);
                vb.z = max3f(B0.z, B1.z, B2.z);
                xC.x = max3f(va.y, va.z, va.w);
                xC.y = max3f(va.z, va.w, vb.x);
                xC.z = max3f(va.w, vb.x, vb.y);
                xC.w = max3f(vb.x, vb.y, vb.z);
                ecB.x = A1.z; ecB.y = A1.w; ecB.z = B1.x; ecB.w = B1.y;
            } else {
                xC = ninf4; ecB = ninf4;
            }

            if (i >= 5) {
                float4 dl;
                dl.x = leaky(acA.x - max3f(xP2.x, xP1.x, xC.x));
                dl.y = leaky(acA.y - max3f(xP2.y, xP1.y, xC.y));
                dl.z = leaky(acA.z - max3f(xP2.z, xP1.z, xC.z));
                dl.w = leaky(acA.w - max3f(xP2.w, xP1.w, xC.w));
                if (step < NUM_ITER) aout4[ob] = ecA;
                if (step == 0) {
                    sk4[ob] = dl;
                } else {
                    float4 gg = sk4[ob];
                    float4 up, gn;
                    up.x = leaky(dl.x - gg.x * dl.x); gn.x = gg.x + up.x;
                    up.y = leaky(dl.y - gg.y * dl.y); gn.y = gg.y + up.y;
                    up.z = leaky(dl.z - gg.z * dl.z); gn.z = gg.z + up.z;
                    up.w = leaky(dl.w - gg.w * dl.w); gn.w = gg.w + up.w;
                    sk4[ob] = gn;
                    if (step == 1)
                        lsum += fabsf(gn.x) + fabsf(gn.y) + fabsf(gn.z) + fabsf(gn.w);
                    else
                        lsum += fabsf(up.x) + fabsf(up.y) + fabsf(up.z) + fabsf(up.w);
                }
                ob += HW4;
            }
            xP2 = xP1; xP1 = xC;
            acA = acB; acB = acC; acC = aCn;
            ecA = ecB;
        }
    }

    // dn reduction: one double atomic per block
    if (step > 0) {
        #pragma unroll
        for (int off = 32; off > 0; off >>= 1)
            lsum += __shfl_down(lsum, off, 64);
        const int lane = t & 63, wid = t >> 6;
        if (lane == 0) wsum[wid] = lsum;
        __syncthreads();
        if (t == 0) {
            float b = wsum[0] + wsum[1] + wsum[2] + wsum[3];
            atomicAdd(&slots[step], (double)b);
        }
    }
}

extern "C" void kernel_launch(void* const* d_in, const int* in_sizes, int n_in,
                              void* d_out, int out_size, void* d_ws, size_t ws_size,
                              hipStream_t stream) {
    const float* img = (const float*)d_in[0];
    float* out = (float*)d_out;
    float* buf0 = (float*)d_ws;
    float* buf1 = buf0 + NTOT;
    double* slots = (double*)(buf1 + NTOT);

    init_slots<<<1, 64, 0, stream>>>(slots);

    dim3 grid(W_DIM / TW, H_DIM / TH, (D_DIM / TDZ) * NIMG);
    for (int s = 0; s <= NUM_ITER; ++s) {
        const float* ain = (s == 0) ? img : ((s & 1) ? buf0 : buf1);
        float* aout = (s & 1) ? buf1 : buf0;
        skel_step<<<grid, 256, 0, stream>>>(ain, aout, out, slots, s);
    }
}

// Round 10
// 409.390 us; speedup vs baseline: 1.1885x; 1.0824x over previous
//
#include <hip/hip_runtime.h>
#include <math.h>

#define D_DIM 128
#define H_DIM 256
#define W_DIM 256
#define HW (H_DIM * W_DIM)
#define HW4 (HW / 4)
#define NIMG 2
#define NPI (D_DIM * HW)
#define NTOT (NIMG * NPI)

#define TDZ 16
#define TH 16
#define TW 64

#define AW4 18   // aS chunks/row: chunk c -> gx = x0-4+4c  (x0-4 .. x0+67)
#define AH 20    // aS rows: gy = y0-2 .. y0+17
#define EW4 17   // eT chunks/row: chunk c -> gx = x0-2+4c  (x0-2 .. x0+65)
#define EH 18    // eT rows: gy = y0-1 .. y0+16

#define NLOAD (AH * AW4)      // 360 real items
#define NLOADP 384            // padded to 6 full waves
#define NERO  (EH * EW4)      // 306
#define NOUT  (TH * (TW/4))   // 256

#define NUM_ITER 20
#define STOP_THRESH 1e-4

__device__ __forceinline__ float min3f(float a, float b, float c) { return fminf(fminf(a, b), c); }
__device__ __forceinline__ float max3f(float a, float b, float c) { return fmaxf(fmaxf(a, b), c); }
__device__ __forceinline__ float leaky(float x) { return fmaxf(x, 0.01f * x); }

// B1: full drain (slice loads must have landed; prior-iter LDS reads done)
#define BAR_VM()  do { asm volatile("s_waitcnt vmcnt(0) lgkmcnt(0)" ::: "memory"); \
                       __builtin_amdgcn_s_barrier(); \
                       __builtin_amdgcn_sched_barrier(0); } while (0)
// B2: LDS-only drain — keeps global_load_lds for slice i+1 in flight
#define BAR_LDS() do { asm volatile("s_waitcnt lgkmcnt(0)" ::: "memory"); \
                       __builtin_amdgcn_s_barrier(); \
                       __builtin_amdgcn_sched_barrier(0); } while (0)

#define GLOAD_LDS(gp, lp) \
    __builtin_amdgcn_global_load_lds((const __attribute__((address_space(1))) unsigned int*)(gp), \
                                     (__attribute__((address_space(3))) unsigned int*)(lp), 16, 0, 0)

__global__ void init_slots(double* slots) {
    int t = threadIdx.x;
    if (t < 32) slots[t] = 0.0;
    if (t >= 32 && t < 36) ((float*)(slots + 32))[t - 32] = INFINITY;  // 16B +INF cell
}

// R7 dataflow (best measured), staging via global_load_lds direct-to-LDS with a
// full iteration of latency cover (B2 does not drain vmcnt), plus early skel
// prefetch. Tile 64x16x16, all 256 threads active in every stage.
__global__ __launch_bounds__(256) void skel_step(
    const float* __restrict__ a_in,
    float* __restrict__ a_out,
    float* __restrict__ skel,
    double* __restrict__ slots,
    int step)
{
    __shared__ float4 aS4[2][NLOADP];  // 12288 B (ping-pong, lds-load dest)
    __shared__ float4 eT4[NERO];       // 4896 B
    __shared__ float wsum[4];
    __shared__ int s_active;

    const int t = threadIdx.x;

    if (t == 0) {
        int act = 1;
        for (int j = 1; j < step; ++j)
            if (!(slots[j] >= STOP_THRESH * (double)NTOT)) { act = 0; break; }
        s_active = act;
    }
    __syncthreads();
    if (!s_active) return;

    const float* infp = (const float*)(slots + 32);

    const int bx = blockIdx.x, by = blockIdx.y;
    const int bz = blockIdx.z & 7, img = blockIdx.z >> 3;
    const int x0 = bx * TW, y0 = by * TH, z0 = bz * TDZ;

    const float* in = a_in + (size_t)img * NPI;
    float4* aout4 = (float4*)(a_out + (size_t)img * NPI);
    float4* sk4 = (float4*)(skel + (size_t)img * NPI);

    // ---- load items: q0 = t (all), q1 = 256+t (t<128; q1>=360 -> pad/INF) ----
    int lOff0; bool lVal0;
    {
        int lr = t / AW4, lc = t - lr * AW4;
        int gy = y0 - 2 + lr, gx = x0 - 4 + 4 * lc;
        lVal0 = ((unsigned)gy < H_DIM) && ((unsigned)gx <= (unsigned)(W_DIM - 4));
        lOff0 = gy * W_DIM + gx;
    }
    const bool hasL1 = t < 128;          // wave-uniform
    int lOff1 = 0; bool lVal1 = false;
    if (hasL1) {
        int q = t + 256;
        int lr = q / AW4, lc = q - lr * AW4;
        int gy = y0 - 2 + lr, gx = x0 - 4 + 4 * lc;
        lVal1 = (q < NLOAD) && ((unsigned)gy < H_DIM) && ((unsigned)gx <= (unsigned)(W_DIM - 4));
        lOff1 = gy * W_DIM + gx;
    }
    const int wbase = (t >> 6) << 6;     // wave-uniform LDS base (element units)

    // ---- erode items ----
    int eRd0; bool sA0, sB0, sC0, sD0;
    {
        int mh = t / EW4, ej = t - mh * EW4;
        eRd0 = mh * AW4 + ej;
        int gy = y0 - 1 + mh;
        bool gok = (unsigned)gy < H_DIM;
        int gxb = x0 - 2 + 4 * ej;
        sA0 = gok && ((unsigned)(gxb + 0) < W_DIM);
        sB0 = gok && ((unsigned)(gxb + 1) < W_DIM);
        sC0 = gok && ((unsigned)(gxb + 2) < W_DIM);
        sD0 = gok && ((unsigned)(gxb + 3) < W_DIM);
    }
    const bool hasE1 = t < (NERO - 256);    // t < 50
    int eRd1 = 0; bool sA1 = false, sB1 = false, sC1 = false, sD1 = false;
    if (hasE1) {
        int q = t + 256;
        int mh = q / EW4, ej = q - mh * EW4;
        eRd1 = mh * AW4 + ej;
        int gy = y0 - 1 + mh;
        bool gok = (unsigned)gy < H_DIM;
        int gxb = x0 - 2 + 4 * ej;
        sA1 = gok && ((unsigned)(gxb + 0) < W_DIM);
        sB1 = gok && ((unsigned)(gxb + 1) < W_DIM);
        sC1 = gok && ((unsigned)(gxb + 2) < W_DIM);
        sD1 = gok && ((unsigned)(gxb + 3) < W_DIM);
    }

    // ---- out item ----
    const int oh = t >> 4, wq = t & 15;
    const int oRd = oh * EW4 + wq;
    const int oAc = (oh + 2) * AW4 + wq + 1;
    size_t ob = ((size_t)z0 * HW + (size_t)(y0 + oh) * W_DIM + (size_t)x0) / 4 + wq;

    const float INF = INFINITY;
    const float4 inf4 = make_float4(INF, INF, INF, INF);
    const float4 ninf4 = make_float4(-INF, -INF, -INF, -INF);
    float4 m0P2 = inf4, m0P1 = inf4, m1P2 = inf4, m1P1 = inf4;
    float4 xP2 = ninf4, xP1 = ninf4;
    float4 acA = make_float4(0, 0, 0, 0), acB = acA, ecA = acA;
    float lsum = 0.f;

    // ---- prologue: issue slice 0 (z = z0-2) into aS4[0] ----
    {
        int z = z0 - 2;
        bool zok = (unsigned)z < D_DIM;
        const float* p = in + (size_t)z * HW;
        const float* s0 = (zok && lVal0) ? (p + lOff0) : infp;
        GLOAD_LDS(s0, &aS4[0][wbase]);
        if (hasL1) {
            const float* s1 = (zok && lVal1) ? (p + lOff1) : infp;
            GLOAD_LDS(s1, &aS4[0][256 + wbase]);
        }
    }

    for (int i = 0; i < TDZ + 4; ++i) {
        const int cur = i & 1;

        BAR_VM();   // B1: aS4[cur] fully loaded; prior-iter LDS reads done

        // early skel prefetch for this iteration's output
        float4 ggPre;
        if (step > 0 && i >= 4) ggPre = sk4[ob];

        // issue slice i+1 into aS4[cur^1] (stays in flight across B2)
        if (i <= TDZ + 2) {
            int z = z0 - 1 + i;
            bool zok = (unsigned)z < D_DIM;
            const float* p = in + (size_t)z * HW;
            const float* s0 = (zok && lVal0) ? (p + lOff0) : infp;
            GLOAD_LDS(s0, &aS4[cur ^ 1][wbase]);
            if (hasL1) {
                const float* s1 = (zok && lVal1) ? (p + lOff1) : infp;
                GLOAD_LDS(s1, &aS4[cur ^ 1][256 + wbase]);
            }
        }

        const bool zp = (unsigned)(z0 - 3 + i) < D_DIM;   // erosion slice in volume?

        // ---- erode: a-slices (i-2,i-1,i) -> erosion z0-3+i -> eT4 ----
        {
            const float4* s = aS4[cur];
            float4 a0 = s[eRd0],           b0 = s[eRd0 + 1];
            float4 a1 = s[eRd0 + AW4],     b1 = s[eRd0 + AW4 + 1];
            float4 a2 = s[eRd0 + 2 * AW4], b2 = s[eRd0 + 2 * AW4 + 1];
            float4 va, vb, mC;
            va.x = min3f(a0.x, a1.x, a2.x);
            va.y = min3f(a0.y, a1.y, a2.y);
            va.z = min3f(a0.z, a1.z, a2.z);
            va.w = min3f(a0.w, a1.w, a2.w);
            vb.x = min3f(b0.x, b1.x, b2.x);
            vb.y = min3f(b0.y, b1.y, b2.y);
            vb.z = min3f(b0.z, b1.z, b2.z);
            mC.x = min3f(va.y, va.z, va.w);
            mC.y = min3f(va.z, va.w, vb.x);
            mC.z = min3f(va.w, vb.x, vb.y);
            mC.w = min3f(vb.x, vb.y, vb.z);
            if (i >= 2 && zp) {
                float4 e;
                e.x = sA0 ? min3f(m0P2.x, m0P1.x, mC.x) : -INF;
                e.y = sB0 ? min3f(m0P2.y, m0P1.y, mC.y) : -INF;
                e.z = sC0 ? min3f(m0P2.z, m0P1.z, mC.z) : -INF;
                e.w = sD0 ? min3f(m0P2.w, m0P1.w, mC.w) : -INF;
                eT4[t] = e;
            }
            m0P2 = m0P1; m0P1 = mC;
        }
        if (hasE1) {
            const float4* s = aS4[cur];
            float4 a0 = s[eRd1],           b0 = s[eRd1 + 1];
            float4 a1 = s[eRd1 + AW4],     b1 = s[eRd1 + AW4 + 1];
            float4 a2 = s[eRd1 + 2 * AW4], b2 = s[eRd1 + 2 * AW4 + 1];
            float4 va, vb, mC;
            va.x = min3f(a0.x, a1.x, a2.x);
            va.y = min3f(a0.y, a1.y, a2.y);
            va.z = min3f(a0.z, a1.z, a2.z);
            va.w = min3f(a0.w, a1.w, a2.w);
            vb.x = min3f(b0.x, b1.x, b2.x);
            vb.y = min3f(b0.y, b1.y, b2.y);
            vb.z = min3f(b0.z, b1.z, b2.z);
            mC.x = min3f(va.y, va.z, va.w);
            mC.y = min3f(va.z, va.w, vb.x);
            mC.z = min3f(va.w, vb.x, vb.y);
            mC.w = min3f(vb.x, vb.y, vb.z);
            if (i >= 2 && zp) {
                float4 e;
                e.x = sA1 ? min3f(m1P2.x, m1P1.x, mC.x) : -INF;
                e.y = sB1 ? min3f(m1P2.y, m1P1.y, mC.y) : -INF;
                e.z = sC1 ? min3f(m1P2.z, m1P1.z, mC.z) : -INF;
                e.w = sD1 ? min3f(m1P2.w, m1P1.w, mC.w) : -INF;
                eT4[t + 256] = e;
            }
            m1P2 = m1P1; m1P1 = mC;
        }

        BAR_LDS();  // B2: eT4 ready (vmcnt NOT drained — slice i+1 still in flight)

        // ---- out: dilate erosion slice z0-3+i; output z0-4+i ----
        {
            const float4 aCn = aS4[cur][oAc];
            float4 xC, ecB;
            if (i >= 2 && zp) {
                float4 A0 = eT4[oRd],           B0 = eT4[oRd + 1];
                float4 A1 = eT4[oRd + EW4],     B1 = eT4[oRd + EW4 + 1];
                float4 A2 = eT4[oRd + 2 * EW4], B2 = eT4[oRd + 2 * EW4 + 1];
                float4 va, vb;
                va.x = max3f(A0.x, A1.x, A2.x);
                va.y = max3f(A0.y, A1.y, A2.y);
                va.z = max3f(A0.z, A1.z, A2.z);
                va.w = max3f(A0.w, A1.w, A2.w);
                vb.x = max3f(B0.x, B1.x, B2.x);
                vb.y = max3f(B0.y, B1.y, B2.y);
                vb.z = max3f(B0.z, B1.z, B2.z);
                xC.x = max3f(va.y, va.z, va.w);
                xC.y = max3f(va.z, va.w, vb.x);
                xC.z = max3f(va.w, vb.x, vb.y);
                xC.w = max3f(vb.x, vb.y, vb.z);
                ecB.x = A1.z; ecB.y = A1.w; ecB.z = B1.x; ecB.w = B1.y;
            } else {
                xC = ninf4; ecB = ninf4;
            }

            if (i >= 4) {
                float4 dl;
                dl.x = leaky(acA.x - max3f(xP2.x, xP1.x, xC.x));
                dl.y = leaky(acA.y - max3f(xP2.y, xP1.y, xC.y));
                dl.z = leaky(acA.z - max3f(xP2.z, xP1.z, xC.z));
                dl.w = leaky(acA.w - max3f(xP2.w, xP1.w, xC.w));
                if (step < NUM_ITER) aout4[ob] = ecA;
                if (step == 0) {
                    sk4[ob] = dl;
                } else {
                    float4 gg = ggPre;
                    float4 up, gn;
                    up.x = leaky(dl.x - gg.x * dl.x); gn.x = gg.x + up.x;
                    up.y = leaky(dl.y - gg.y * dl.y); gn.y = gg.y + up.y;
                    up.z = leaky(dl.z - gg.z * dl.z); gn.z = gg.z + up.z;
                    up.w = leaky(dl.w - gg.w * dl.w); gn.w = gg.w + up.w;
                    sk4[ob] = gn;
                    if (step == 1)
                        lsum += fabsf(gn.x) + fabsf(gn.y) + fabsf(gn.z) + fabsf(gn.w);
                    else
                        lsum += fabsf(up.x) + fabsf(up.y) + fabsf(up.z) + fabsf(up.w);
                }
                ob += HW4;
            }
            xP2 = xP1; xP1 = xC;
            acA = acB; acB = aCn;
            ecA = ecB;
        }
    }

    // dn reduction: one double atomic per block
    if (step > 0) {
        #pragma unroll
        for (int off = 32; off > 0; off >>= 1)
            lsum += __shfl_down(lsum, off, 64);
        const int lane = t & 63, wid = t >> 6;
        if (lane == 0) wsum[wid] = lsum;
        __syncthreads();
        if (t == 0) {
            float b = wsum[0] + wsum[1] + wsum[2] + wsum[3];
            atomicAdd(&slots[step], (double)b);
        }
    }
}

extern "C" void kernel_launch(void* const* d_in, const int* in_sizes, int n_in,
                              void* d_out, int out_size, void* d_ws, size_t ws_size,
                              hipStream_t stream) {
    const float* img = (const float*)d_in[0];
    float* out = (float*)d_out;
    float* buf0 = (float*)d_ws;
    float* buf1 = buf0 + NTOT;
    double* slots = (double*)(buf1 + NTOT);

    init_slots<<<1, 64, 0, stream>>>(slots);

    dim3 grid(W_DIM / TW, H_DIM / TH, (D_DIM / TDZ) * NIMG);
    for (int s = 0; s <= NUM_ITER; ++s) {
        const float* ain = (s == 0) ? img : ((s & 1) ? buf0 : buf1);
        float* aout = (s & 1) ? buf1 : buf0;
        skel_step<<<grid, 256, 0, stream>>>(ain, aout, out, slots, s);
    }
}

// Round 11
// 385.180 us; speedup vs baseline: 1.2632x; 1.0629x over previous
//
#include <hip/hip_runtime.h>
#include <math.h>

#define D_DIM 128
#define H_DIM 256
#define W_DIM 256
#define HW (H_DIM * W_DIM)
#define HW4 (HW / 4)
#define NIMG 2
#define NPI (D_DIM * HW)
#define NTOT (NIMG * NPI)

#define TDZ 16
#define TH 16
#define TW 64

#define AW4 18   // aS chunks/row: chunk c -> gx = x0-4+4c  (x0-4 .. x0+67)
#define AH 20    // aS rows: gy = y0-2 .. y0+17
#define EW4 17   // eT chunks/row: chunk c -> gx = x0-2+4c  (x0-2 .. x0+65)
#define EH 18    // eT rows: gy = y0-1 .. y0+16

#define NLOAD (AH * AW4)      // 360 real items
#define NLOADP 384            // padded to 6 full waves
#define NERO  (EH * EW4)      // 306
#define NOUT  (TH * (TW/4))   // 256

#define NUM_ITER 20
#define STOP_THRESH 1e-4

__device__ __forceinline__ float min3f(float a, float b, float c) { return fminf(fminf(a, b), c); }
__device__ __forceinline__ float max3f(float a, float b, float c) { return fmaxf(fmaxf(a, b), c); }
__device__ __forceinline__ float leaky(float x) { return fmaxf(x, 0.01f * x); }

// B1 variants: drain gloads but leave prior-iter stores in flight where safe.
// Issue order per iter: [ggPre][g0][g1][erode][B2][stores x2]. At the next B1,
// waiting vmcnt(N_stores) retires everything up to the last gload (oldest-first
// counting), so aS4 is guaranteed loaded while store-acks stay pending.
#define BAR_FULL() do { asm volatile("s_waitcnt vmcnt(0) lgkmcnt(0)" ::: "memory"); \
                        __builtin_amdgcn_s_barrier(); \
                        __builtin_amdgcn_sched_barrier(0); } while (0)
#define BAR_VM2()  do { asm volatile("s_waitcnt vmcnt(2) lgkmcnt(0)" ::: "memory"); \
                        __builtin_amdgcn_s_barrier(); \
                        __builtin_amdgcn_sched_barrier(0); } while (0)
#define BAR_VM1()  do { asm volatile("s_waitcnt vmcnt(1) lgkmcnt(0)" ::: "memory"); \
                        __builtin_amdgcn_s_barrier(); \
                        __builtin_amdgcn_sched_barrier(0); } while (0)
// B2: LDS-only drain — keeps global_load_lds for slice i+1 in flight
#define BAR_LDS() do { asm volatile("s_waitcnt lgkmcnt(0)" ::: "memory"); \
                       __builtin_amdgcn_s_barrier(); \
                       __builtin_amdgcn_sched_barrier(0); } while (0)

#define GLOAD_LDS(gp, lp) \
    __builtin_amdgcn_global_load_lds((const __attribute__((address_space(1))) unsigned int*)(gp), \
                                     (__attribute__((address_space(3))) unsigned int*)(lp), 16, 0, 0)

__global__ void init_slots(double* slots) {
    int t = threadIdx.x;
    if (t < 32) slots[t] = 0.0;
    if (t >= 32 && t < 36) ((float*)(slots + 32))[t - 32] = INFINITY;  // 16B +INF cell
}

// R10 structure + counted-vmcnt barriers + XCD-aware block swizzle.
// Tile 64x16x16, all 256 threads active in every stage.
__global__ __launch_bounds__(256) void skel_step(
    const float* __restrict__ a_in,
    float* __restrict__ a_out,
    float* __restrict__ skel,
    double* __restrict__ slots,
    int step)
{
    __shared__ float4 aS4[2][NLOADP];  // 12288 B (ping-pong, lds-load dest)
    __shared__ float4 eT4[NERO];       // 4896 B
    __shared__ float wsum[4];
    __shared__ int s_active;

    const int t = threadIdx.x;

    if (t == 0) {
        int act = 1;
        for (int j = 1; j < step; ++j)
            if (!(slots[j] >= STOP_THRESH * (double)NTOT)) { act = 0; break; }
        s_active = act;
    }
    __syncthreads();
    if (!s_active) return;

    const float* infp = (const float*)(slots + 32);

    // XCD-aware swizzle: hardware round-robins linear block id over 8 XCDs;
    // remap so XCD k owns swz in [128k,128(k+1)) = full xy coverage of 2
    // adjacent z-slabs -> halo reads hit the same XCD's L2.
    const int lid = blockIdx.x + 4 * (blockIdx.y + 16 * blockIdx.z);  // grid (4,16,16)
    const int swz = (lid & 7) * 128 + (lid >> 3);
    const int bx = swz & 3;
    const int by = (swz >> 2) & 15;
    const int zz = swz >> 6;           // 0..15
    const int bz = zz & 7, img = zz >> 3;
    const int x0 = bx * TW, y0 = by * TH, z0 = bz * TDZ;

    const float* in = a_in + (size_t)img * NPI;
    float4* aout4 = (float4*)(a_out + (size_t)img * NPI);
    float4* sk4 = (float4*)(skel + (size_t)img * NPI);

    // ---- load items: q0 = t (all), q1 = 256+t (t<128; q1>=360 -> pad/INF) ----
    int lOff0; bool lVal0;
    {
        int lr = t / AW4, lc = t - lr * AW4;
        int gy = y0 - 2 + lr, gx = x0 - 4 + 4 * lc;
        lVal0 = ((unsigned)gy < H_DIM) && ((unsigned)gx <= (unsigned)(W_DIM - 4));
        lOff0 = gy * W_DIM + gx;
    }
    const bool hasL1 = t < 128;          // wave-uniform
    int lOff1 = 0; bool lVal1 = false;
    if (hasL1) {
        int q = t + 256;
        int lr = q / AW4, lc = q - lr * AW4;
        int gy = y0 - 2 + lr, gx = x0 - 4 + 4 * lc;
        lVal1 = (q < NLOAD) && ((unsigned)gy < H_DIM) && ((unsigned)gx <= (unsigned)(W_DIM - 4));
        lOff1 = gy * W_DIM + gx;
    }
    const int wbase = (t >> 6) << 6;     // wave-uniform LDS base (element units)

    // ---- erode items ----
    int eRd0; bool sA0, sB0, sC0, sD0;
    {
        int mh = t / EW4, ej = t - mh * EW4;
        eRd0 = mh * AW4 + ej;
        int gy = y0 - 1 + mh;
        bool gok = (unsigned)gy < H_DIM;
        int gxb = x0 - 2 + 4 * ej;
        sA0 = gok && ((unsigned)(gxb + 0) < W_DIM);
        sB0 = gok && ((unsigned)(gxb + 1) < W_DIM);
        sC0 = gok && ((unsigned)(gxb + 2) < W_DIM);
        sD0 = gok && ((unsigned)(gxb + 3) < W_DIM);
    }
    const bool hasE1 = t < (NERO - 256);    // t < 50
    int eRd1 = 0; bool sA1 = false, sB1 = false, sC1 = false, sD1 = false;
    if (hasE1) {
        int q = t + 256;
        int mh = q / EW4, ej = q - mh * EW4;
        eRd1 = mh * AW4 + ej;
        int gy = y0 - 1 + mh;
        bool gok = (unsigned)gy < H_DIM;
        int gxb = x0 - 2 + 4 * ej;
        sA1 = gok && ((unsigned)(gxb + 0) < W_DIM);
        sB1 = gok && ((unsigned)(gxb + 1) < W_DIM);
        sC1 = gok && ((unsigned)(gxb + 2) < W_DIM);
        sD1 = gok && ((unsigned)(gxb + 3) < W_DIM);
    }

    // ---- out item ----
    const int oh = t >> 4, wq = t & 15;
    const int oRd = oh * EW4 + wq;
    const int oAc = (oh + 2) * AW4 + wq + 1;
    size_t ob = ((size_t)z0 * HW + (size_t)(y0 + oh) * W_DIM + (size_t)x0) / 4 + wq;

    const float INF = INFINITY;
    const float4 inf4 = make_float4(INF, INF, INF, INF);
    const float4 ninf4 = make_float4(-INF, -INF, -INF, -INF);
    float4 m0P2 = inf4, m0P1 = inf4, m1P2 = inf4, m1P1 = inf4;
    float4 xP2 = ninf4, xP1 = ninf4;
    float4 acA = make_float4(0, 0, 0, 0), acB = acA, ecA = acA;
    float lsum = 0.f;

    // ---- prologue: issue slice 0 (z = z0-2) into aS4[0] ----
    {
        int z = z0 - 2;
        bool zok = (unsigned)z < D_DIM;
        const float* p = in + (size_t)z * HW;
        const float* s0 = (zok && lVal0) ? (p + lOff0) : infp;
        GLOAD_LDS(s0, &aS4[0][wbase]);
        if (hasL1) {
            const float* s1 = (zok && lVal1) ? (p + lOff1) : infp;
            GLOAD_LDS(s1, &aS4[0][256 + wbase]);
        }
    }

    for (int i = 0; i < TDZ + 4; ++i) {
        const int cur = i & 1;

        // B1: aS4[cur] loaded. i<5: nothing but gloads outstanding -> full
        // drain. i>=5: leave prior-iter stores (2; 1 at step 20) in flight.
        if (i < 5) { BAR_FULL(); }
        else if (step == NUM_ITER) { BAR_VM1(); }
        else { BAR_VM2(); }

        // early skel prefetch for this iteration's output
        float4 ggPre;
        if (step > 0 && i >= 4) ggPre = sk4[ob];

        // issue slice i+1 into aS4[cur^1] (stays in flight across B2)
        if (i <= TDZ + 2) {
            int z = z0 - 1 + i;
            bool zok = (unsigned)z < D_DIM;
            const float* p = in + (size_t)z * HW;
            const float* s0 = (zok && lVal0) ? (p + lOff0) : infp;
            GLOAD_LDS(s0, &aS4[cur ^ 1][wbase]);
            if (hasL1) {
                const float* s1 = (zok && lVal1) ? (p + lOff1) : infp;
                GLOAD_LDS(s1, &aS4[cur ^ 1][256 + wbase]);
            }
        }

        const bool zp = (unsigned)(z0 - 3 + i) < D_DIM;   // erosion slice in volume?

        // ---- erode: a-slices (i-2,i-1,i) -> erosion z0-3+i -> eT4 ----
        {
            const float4* s = aS4[cur];
            float4 a0 = s[eRd0],           b0 = s[eRd0 + 1];
            float4 a1 = s[eRd0 + AW4],     b1 = s[eRd0 + AW4 + 1];
            float4 a2 = s[eRd0 + 2 * AW4], b2 = s[eRd0 + 2 * AW4 + 1];
            float4 va, vb, mC;
            va.x = min3f(a0.x, a1.x, a2.x);
            va.y = min3f(a0.y, a1.y, a2.y);
            va.z = min3f(a0.z, a1.z, a2.z);
            va.w = min3f(a0.w, a1.w, a2.w);
            vb.x = min3f(b0.x, b1.x, b2.x);
            vb.y = min3f(b0.y, b1.y, b2.y);
            vb.z = min3f(b0.z, b1.z, b2.z);
            mC.x = min3f(va.y, va.z, va.w);
            mC.y = min3f(va.z, va.w, vb.x);
            mC.z = min3f(va.w, vb.x, vb.y);
            mC.w = min3f(vb.x, vb.y, vb.z);
            if (i >= 2 && zp) {
                float4 e;
                e.x = sA0 ? min3f(m0P2.x, m0P1.x, mC.x) : -INF;
                e.y = sB0 ? min3f(m0P2.y, m0P1.y, mC.y) : -INF;
                e.z = sC0 ? min3f(m0P2.z, m0P1.z, mC.z) : -INF;
                e.w = sD0 ? min3f(m0P2.w, m0P1.w, mC.w) : -INF;
                eT4[t] = e;
            }
            m0P2 = m0P1; m0P1 = mC;
        }
        if (hasE1) {
            const float4* s = aS4[cur];
            float4 a0 = s[eRd1],           b0 = s[eRd1 + 1];
            float4 a1 = s[eRd1 + AW4],     b1 = s[eRd1 + AW4 + 1];
            float4 a2 = s[eRd1 + 2 * AW4], b2 = s[eRd1 + 2 * AW4 + 1];
            float4 va, vb, mC;
            va.x = min3f(a0.x, a1.x, a2.x);
            va.y = min3f(a0.y, a1.y, a2.y);
            va.z = min3f(a0.z, a1.z, a2.z);
            va.w = min3f(a0.w, a1.w, a2.w);
            vb.x = min3f(b0.x, b1.x, b2.x);
            vb.y = min3f(b0.y, b1.y, b2.y);
            vb.z = min3f(b0.z, b1.z, b2.z);
            mC.x = min3f(va.y, va.z, va.w);
            mC.y = min3f(va.z, va.w, vb.x);
            mC.z = min3f(va.w, vb.x, vb.y);
            mC.w = min3f(vb.x, vb.y, vb.z);
            if (i >= 2 && zp) {
                float4 e;
                e.x = sA1 ? min3f(m1P2.x, m1P1.x, mC.x) : -INF;
                e.y = sB1 ? min3f(m1P2.y, m1P1.y, mC.y) : -INF;
                e.z = sC1 ? min3f(m1P2.z, m1P1.z, mC.z) : -INF;
                e.w = sD1 ? min3f(m1P2.w, m1P1.w, mC.w) : -INF;
                eT4[t + 256] = e;
            }
            m1P2 = m1P1; m1P1 = mC;
        }

        BAR_LDS();  // B2: eT4 ready (vmcnt NOT drained — slice i+1 still in flight)

        // ---- out: dilate erosion slice z0-3+i; output z0-4+i ----
        {
            const float4 aCn = aS4[cur][oAc];
            float4 xC, ecB;
            if (i >= 2 && zp) {
                float4 A0 = eT4[oRd],           B0 = eT4[oRd + 1];
                float4 A1 = eT4[oRd + EW4],     B1 = eT4[oRd + EW4 + 1];
                float4 A2 = eT4[oRd + 2 * EW4], B2 = eT4[oRd + 2 * EW4 + 1];
                float4 va, vb;
                va.x = max3f(A0.x, A1.x, A2.x);
                va.y = max3f(A0.y, A1.y, A2.y);
                va.z = max3f(A0.z, A1.z, A2.z);
                va.w = max3f(A0.w, A1.w, A2.w);
                vb.x = max3f(B0.x, B1.x, B2.x);
                vb.y = max3f(B0.y, B1.y, B2.y);
                vb.z = max3f(B0.z, B1.z, B2.z);
                xC.x = max3f(va.y, va.z, va.w);
                xC.y = max3f(va.z, va.w, vb.x);
                xC.z = max3f(va.w, vb.x, vb.y);
                xC.w = max3f(vb.x, vb.y, vb.z);
                ecB.x = A1.z; ecB.y = A1.w; ecB.z = B1.x; ecB.w = B1.y;
            } else {
                xC = ninf4; ecB = ninf4;
            }

            if (i >= 4) {
                float4 dl;
                dl.x = leaky(acA.x - max3f(xP2.x, xP1.x, xC.x));
                dl.y = leaky(acA.y - max3f(xP2.y, xP1.y, xC.y));
                dl.z = leaky(acA.z - max3f(xP2.z, xP1.z, xC.z));
                dl.w = leaky(acA.w - max3f(xP2.w, xP1.w, xC.w));
                if (step < NUM_ITER) aout4[ob] = ecA;
                if (step == 0) {
                    sk4[ob] = dl;
                } else {
                    float4 gg = ggPre;
                    float4 up, gn;
                    up.x = leaky(dl.x - gg.x * dl.x); gn.x = gg.x + up.x;
                    up.y = leaky(dl.y - gg.y * dl.y); gn.y = gg.y + up.y;
                    up.z = leaky(dl.z - gg.z * dl.z); gn.z = gg.z + up.z;
                    up.w = leaky(dl.w - gg.w * dl.w); gn.w = gg.w + up.w;
                    sk4[ob] = gn;
                    if (step == 1)
                        lsum += fabsf(gn.x) + fabsf(gn.y) + fabsf(gn.z) + fabsf(gn.w);
                    else
                        lsum += fabsf(up.x) + fabsf(up.y) + fabsf(up.z) + fabsf(up.w);
                }
                ob += HW4;
            }
            xP2 = xP1; xP1 = xC;
            acA = acB; acB = aCn;
            ecA = ecB;
        }
    }

    // dn reduction: one double atomic per block
    if (step > 0) {
        #pragma unroll
        for (int off = 32; off > 0; off >>= 1)
            lsum += __shfl_down(lsum, off, 64);
        const int lane = t & 63, wid = t >> 6;
        if (lane == 0) wsum[wid] = lsum;
        __syncthreads();
        if (t == 0) {
            float b = wsum[0] + wsum[1] + wsum[2] + wsum[3];
            atomicAdd(&slots[step], (double)b);
        }
    }
}

extern "C" void kernel_launch(void* const* d_in, const int* in_sizes, int n_in,
                              void* d_out, int out_size, void* d_ws, size_t ws_size,
                              hipStream_t stream) {
    const float* img = (const float*)d_in[0];
    float* out = (float*)d_out;
    float* buf0 = (float*)d_ws;
    float* buf1 = buf0 + NTOT;
    double* slots = (double*)(buf1 + NTOT);

    init_slots<<<1, 64, 0, stream>>>(slots);

    dim3 grid(W_DIM / TW, H_DIM / TH, (D_DIM / TDZ) * NIMG);
    for (int s = 0; s <= NUM_ITER; ++s) {
        const float* ain = (s == 0) ? img : ((s & 1) ? buf0 : buf1);
        float* aout = (s & 1) ? buf1 : buf0;
        skel_step<<<grid, 256, 0, stream>>>(ain, aout, out, slots, s);
    }
}